// Round 10
// baseline (216.277 us; speedup 1.0000x reference)
//
#include <hip/hip_runtime.h>
#include <hip/hip_bf16.h>

#define NROW 4096
#define D 128
#define TOT 8192
#define PRESCALE 1.69864407f  // sqrt(2*log2(e)): acc = logit * log2(e)
#define LN2 0.69314718055994531f
#define GRID_G 2048

typedef __attribute__((ext_vector_type(8))) short bf16x8;
typedef __attribute__((ext_vector_type(4))) float f32x4;

static __device__ __forceinline__ float fast_exp2(float x) {
  return __builtin_amdgcn_exp2f(x);
}
static __device__ __forceinline__ float fast_log2(float x) {
  return __builtin_amdgcn_logf(x);
}
static __device__ __forceinline__ unsigned short f2bf(float x) {
  unsigned u = __float_as_uint(x);
  return (unsigned short)((u + 0x7fffu + ((u >> 16) & 1u)) >> 16);
}

// Kernel 1: normalize -> prescaled bf16 Z; exact fp32 pos logits; zero
// rowsum + completion counter. (Proven correct rounds 1-7; unchanged.)
__global__ __launch_bounds__(256) void k_norm(
    const float* __restrict__ ei, const float* __restrict__ ej,
    unsigned short* __restrict__ Zp, float* __restrict__ pos,
    float* __restrict__ rowsum, unsigned* __restrict__ ctr) {
  int gid = blockIdx.x * 256 + (int)threadIdx.x;
  if (gid < TOT) rowsum[gid] = 0.0f;
  if (gid == TOT) *ctr = 0u;

  int wid = threadIdx.x >> 6;
  int lane = threadIdx.x & 63;
  int r = blockIdx.x * 4 + wid;
  const float2 xi = *(const float2*)(ei + (size_t)r * D + lane * 2);
  const float2 xj = *(const float2*)(ej + (size_t)r * D + lane * 2);
  float si = xi.x * xi.x + xi.y * xi.y;
  float sj = xj.x * xj.x + xj.y * xj.y;
  float dd = xi.x * xj.x + xi.y * xj.y;
#pragma unroll
  for (int m = 32; m >= 1; m >>= 1) {
    si += __shfl_xor(si, m, 64);
    sj += __shfl_xor(sj, m, 64);
    dd += __shfl_xor(dd, m, 64);
  }
  float ri = rsqrtf(si); ri = ri * (1.5f - 0.5f * si * ri * ri);
  float rj = rsqrtf(sj); rj = rj * (1.5f - 0.5f * sj * rj * rj);
  ((unsigned*)(Zp + (size_t)r * D))[lane] =
      (unsigned)f2bf(xi.x * ri * PRESCALE) | ((unsigned)f2bf(xi.y * ri * PRESCALE) << 16);
  ((unsigned*)(Zp + (size_t)(r + NROW) * D))[lane] =
      (unsigned)f2bf(xj.x * rj * PRESCALE) | ((unsigned)f2bf(xj.y * rj * PRESCALE) << 16);
  if (lane == 0) pos[r] = 2.0f * dd * ri * rj;
}

static __device__ __forceinline__ void loadB(bf16x8 (&buf)[4],
                                             const unsigned short* zbl, int t) {
#pragma unroll
  for (int kk = 0; kk < 4; ++kk)
    buf[kk] = *(const bf16x8*)(zbl + t * 2048 + kk * 32);
}

static __device__ __forceinline__ void computeT(const bf16x8 (&af)[2][4],
                                                const bf16x8 (&bv)[4],
                                                float (&sums)[2][4], int dq,
                                                int lo, int hi) {
  f32x4 acc[2];
  acc[0] = (f32x4){0.f, 0.f, 0.f, 0.f};
  acc[1] = (f32x4){0.f, 0.f, 0.f, 0.f};
#pragma unroll
  for (int kk = 0; kk < 4; ++kk) {
#pragma unroll
    for (int g = 0; g < 2; ++g)
      acc[g] = __builtin_amdgcn_mfma_f32_16x16x32_bf16(af[g][kk], bv[kk], acc[g], 0, 0, 0);
  }
#pragma unroll
  for (int g = 0; g < 2; ++g)
#pragma unroll
    for (int r = 0; r < 4; ++r) {
      float e = fast_exp2(acc[g][r]);
      if (g == dq && lo == hi * 4 + r) e = 0.0f;  // mask self (diagonal)
      sums[g][r] += e;
    }
}

// Kernel 2: fused Z*Z^T + exp + rowsum; last block folds the final loss.
// 2048 blocks = 64 row-groups (128 rows) x 32 col-slices (256 cols, XCD-
// pinned). 4 waves x 32 rows; A (32 regs) held; B register-double-buffered
// (no LDS, no barriers — latency-bound regime: round 1's barrier-free 48 us
// beat every staged variant). ~92 regs under the (256,4)=128 cap: no spill.
__global__ __launch_bounds__(256, 4) void k_gemm(
    const unsigned short* __restrict__ Zp, float* __restrict__ rowsum,
    const float* __restrict__ pos, unsigned* __restrict__ ctr,
    float* __restrict__ out) {
  const int tid = (int)threadIdx.x;
  const int wid = tid >> 6, lane = tid & 63;
  const int lo = lane & 15, hi = lane >> 4;
  const int b = (int)blockIdx.x;
  const int cs = (b & 7) * 4 + ((b >> 3) & 3);  // col-slice 0..31, XCD-pinned
  const int rb = b >> 5;                        // row-group 0..63
  const int rowbase = rb * 128 + wid * 32;

  // A fragments: 32 rows x 128 k per wave (32 regs)
  bf16x8 af[2][4];
#pragma unroll
  for (int g = 0; g < 2; ++g) {
    const unsigned short* za = Zp + (size_t)(rowbase + g * 16 + lo) * D + hi * 8;
#pragma unroll
    for (int kk = 0; kk < 4; ++kk) af[g][kk] = *(const bf16x8*)(za + kk * 32);
  }

  // B: all 4 waves read identical addresses (L1 broadcast); tile t = 16 cols
  const unsigned short* zbl = Zp + ((size_t)cs * 256 + lo) * D + hi * 8;

  float sums[2][4];
#pragma unroll
  for (int g = 0; g < 2; ++g)
#pragma unroll
    for (int r = 0; r < 4; ++r) sums[g][r] = 0.0f;

  // dq for tile t: diag subtile hits wave row-group g when
  // cs*16 + t == rb*8 + wid*2 + g  (wave-uniform)
  const int dqb = cs * 16 - rb * 8 - wid * 2;

  // register double-buffered pipeline over 16 tiles (static indices only)
  bf16x8 bA[4], bB[4];
  loadB(bA, zbl, 0);
#pragma unroll
  for (int t = 0; t < 16; t += 2) {
    loadB(bB, zbl, t + 1);
    computeT(af, bA, sums, dqb + t, lo, hi);
    if (t + 2 < 16) loadB(bA, zbl, t + 2);
    computeT(af, bB, sums, dqb + t + 1, lo, hi);
  }

  // reduce 16 column-slots per row; one atomic per row per wave
#pragma unroll
  for (int g = 0; g < 2; ++g)
#pragma unroll
    for (int r = 0; r < 4; ++r) {
      float v = sums[g][r];
      v += __shfl_xor(v, 1, 64);
      v += __shfl_xor(v, 2, 64);
      v += __shfl_xor(v, 4, 64);
      v += __shfl_xor(v, 8, 64);
      if (lo == 0) atomicAdd(&rowsum[rowbase + g * 16 + hi * 4 + r], v);
    }

  // last-block-done final reduction (proven since round 2)
  __syncthreads();
  __shared__ unsigned slast;
  if (tid == 0) {
    __threadfence();
    slast = atomicAdd(ctr, 1u);
  }
  __syncthreads();
  if (slast == GRID_G - 1) {
    __threadfence();  // acquire side
    float s1 = 0.0f, s2 = 0.0f;
    for (int k = tid; k < TOT; k += 256)
      s1 += fast_log2(__hip_atomic_load(&rowsum[k], __ATOMIC_RELAXED,
                                        __HIP_MEMORY_SCOPE_AGENT));
    for (int k = tid; k < NROW; k += 256) s2 += pos[k];
    float c = s1 * (LN2 / (float)TOT) - s2 * (1.0f / (float)NROW);
#pragma unroll
    for (int m = 32; m >= 1; m >>= 1) c += __shfl_xor(c, m, 64);
    __shared__ float ws4[4];
    if (lane == 0) ws4[wid] = c;
    __syncthreads();
    if (tid == 0) out[0] = ws4[0] + ws4[1] + ws4[2] + ws4[3];
  }
}

extern "C" void kernel_launch(void* const* d_in, const int* in_sizes, int n_in,
                              void* d_out, int out_size, void* d_ws, size_t ws_size,
                              hipStream_t stream) {
  const float* ei = (const float*)d_in[0];
  const float* ej = (const float*)d_in[1];
  float* out = (float*)d_out;
  float* rowsum = (float*)d_ws;                                   // 8192 f32
  float* pos = (float*)((char*)d_ws + TOT * 4);                   // 4096 f32
  unsigned* ctr = (unsigned*)((char*)d_ws + TOT * 4 + NROW * 4);  // 1 u32
  unsigned short* Zp =
      (unsigned short*)((char*)d_ws + TOT * 4 + NROW * 4 + 256);  // 8192x128 bf16

  k_norm<<<NROW / 4, 256, 0, stream>>>(ei, ej, Zp, pos, rowsum, ctr);
  k_gemm<<<GRID_G, 256, 0, stream>>>(Zp, rowsum, pos, ctr, out);
}